// Round 2
// baseline (780.590 us; speedup 1.0000x reference)
//
#include <hip/hip_runtime.h>

#define D 64

// ---------------- CSR build ----------------

__global__ void k_zero(int* __restrict__ p, int n) {
    int i = blockIdx.x * blockDim.x + threadIdx.x;
    if (i < n) p[i] = 0;
}

__global__ void k_hist(const int* __restrict__ dst, int* __restrict__ cnt, int e) {
    int i = blockIdx.x * blockDim.x + threadIdx.x;
    if (i < e) atomicAdd(&cnt[dst[i]], 1);
}

// Per-block exclusive partial prefix over 2048 elements (8/thread), block sums out.
__global__ void k_scan1(const int* __restrict__ cnt, int* __restrict__ rowptr,
                        int* __restrict__ bsums, int n) {
    __shared__ int lds[256];
    int tid = threadIdx.x;
    int base = blockIdx.x * 2048 + tid * 8;
    int v[8];
    int s = 0;
#pragma unroll
    for (int j = 0; j < 8; ++j) {
        int idx = base + j;
        v[j] = (idx < n) ? cnt[idx] : 0;
        s += v[j];
    }
    lds[tid] = s;
    __syncthreads();
    for (int off = 1; off < 256; off <<= 1) {
        int t = (tid >= off) ? lds[tid - off] : 0;
        __syncthreads();
        lds[tid] += t;
        __syncthreads();
    }
    int run = lds[tid] - s;  // exclusive prefix of this thread's chunk within block
#pragma unroll
    for (int j = 0; j < 8; ++j) {
        int idx = base + j;
        if (idx < n) rowptr[idx] = run;
        run += v[j];
    }
    if (tid == 255) bsums[blockIdx.x] = lds[255];
}

// Add block offsets (each 256-thread block lies entirely within one 2048 region),
// emit cursor copy and dinv = rsqrt(deg+1).
__global__ void k_scan2(int* __restrict__ rowptr, int* __restrict__ cursor,
                        float* __restrict__ dinv, const int* __restrict__ cnt,
                        const int* __restrict__ bsums, int n, int nb) {
    __shared__ int s_off;
    int i = blockIdx.x * blockDim.x + threadIdx.x;
    int b = (blockIdx.x * blockDim.x) >> 11;
    if (threadIdx.x == 0) {
        int o = 0;
        for (int j = 0; j < b; ++j) o += bsums[j];
        s_off = o;
    }
    __syncthreads();
    if (i < n) {
        int rp = rowptr[i] + s_off;
        rowptr[i] = rp;
        cursor[i] = rp;
        dinv[i] = rsqrtf((float)(cnt[i] + 1));
    }
    if (blockIdx.x == 0 && threadIdx.x == 0) {
        int t = 0;
        for (int j = 0; j < nb; ++j) t += bsums[j];
        rowptr[n] = t;
    }
}

__global__ void k_fill(const int* __restrict__ src, const int* __restrict__ dst,
                       int* __restrict__ cursor, int* __restrict__ csr, int e) {
    int i = blockIdx.x * blockDim.x + threadIdx.x;
    if (i < e) {
        int d = dst[i];
        int pos = atomicAdd(&cursor[d], 1);
        csr[pos] = src[i];
    }
}

// ---------------- compute ----------------

// G[r][c] = dinv[r] * sum_k X[r][k] * W[k][c]     (32 rows per block, 256 threads)
__global__ void k_gemm_scale(const float* __restrict__ X, const float* __restrict__ W,
                             const float* __restrict__ dinv, float* __restrict__ G, int n) {
    __shared__ float Ws[D][D];   // 16 KB
    __shared__ float Xs[32][D];  // 8 KB
    int tid = threadIdx.x;
    int col = tid & 63;
    int rq = tid >> 6;  // wave id, 0..3
    int rowbase = blockIdx.x * 32;

    // stage W (coalesced float4)
    for (int i = tid; i < (D * D) / 4; i += 256)
        reinterpret_cast<float4*>(&Ws[0][0])[i] = reinterpret_cast<const float4*>(W)[i];

    // stage 32 rows of X
    if (rowbase + 32 <= n) {
        const float4* xp = reinterpret_cast<const float4*>(X + (size_t)rowbase * D);
        for (int i = tid; i < (32 * D) / 4; i += 256)
            reinterpret_cast<float4*>(&Xs[0][0])[i] = xp[i];
    } else {
        for (int i = tid; i < 32 * D; i += 256) {
            int r = rowbase + (i >> 6);
            Xs[i >> 6][i & 63] = (r < n) ? X[(size_t)r * D + (i & 63)] : 0.f;
        }
    }
    __syncthreads();

    float acc[8];
#pragma unroll
    for (int j = 0; j < 8; ++j) acc[j] = 0.f;

#pragma unroll
    for (int k4 = 0; k4 < D; k4 += 4) {
        float w0 = Ws[k4 + 0][col];
        float w1 = Ws[k4 + 1][col];
        float w2 = Ws[k4 + 2][col];
        float w3 = Ws[k4 + 3][col];
#pragma unroll
        for (int j = 0; j < 8; ++j) {
            float4 xv = *reinterpret_cast<const float4*>(&Xs[(rq << 3) + j][k4]);
            acc[j] += xv.x * w0 + xv.y * w1 + xv.z * w2 + xv.w * w3;
        }
    }

#pragma unroll
    for (int j = 0; j < 8; ++j) {
        int r = rowbase + (rq << 3) + j;
        if (r < n) G[(size_t)r * D + col] = acc[j] * dinv[r];
    }
}

// out[i][c] = dinv[i] * (G[i][c] + sum_{e in CSR row i} G[src_e][c]) + b[c]; optional relu.
// One wave per row; lane = column.
__global__ void k_agg(const float* __restrict__ G, const int* __restrict__ rowptr,
                      const int* __restrict__ csr, const float* __restrict__ dinv,
                      const float* __restrict__ bias, float* __restrict__ out,
                      int n, int do_relu) {
    int wid = (blockIdx.x * blockDim.x + threadIdx.x) >> 6;
    int lane = threadIdx.x & 63;
    if (wid >= n) return;
    int beg = rowptr[wid];
    int end = rowptr[wid + 1];
    float acc = G[(size_t)wid * D + lane];  // self-loop term
    int e = beg;
    for (; e + 4 <= end; e += 4) {
        int s0 = csr[e + 0];
        int s1 = csr[e + 1];
        int s2 = csr[e + 2];
        int s3 = csr[e + 3];
        float v0 = G[(size_t)s0 * D + lane];
        float v1 = G[(size_t)s1 * D + lane];
        float v2 = G[(size_t)s2 * D + lane];
        float v3 = G[(size_t)s3 * D + lane];
        acc += v0;
        acc += v1;
        acc += v2;
        acc += v3;
    }
    for (; e < end; ++e) acc += G[(size_t)csr[e] * D + lane];
    float v = acc * dinv[wid] + bias[lane];
    if (do_relu) v = fmaxf(v, 0.f);
    out[(size_t)wid * D + lane] = v;
}

// ---------------- launch ----------------

extern "C" void kernel_launch(void* const* d_in, const int* in_sizes, int n_in,
                              void* d_out, int out_size, void* d_ws, size_t ws_size,
                              hipStream_t stream) {
    const int* ei = (const int*)d_in[0];
    const float* emb = (const float*)d_in[1];
    const float* W1 = (const float*)d_in[2];
    const float* b1 = (const float*)d_in[3];
    const float* W2 = (const float*)d_in[4];
    const float* b2 = (const float*)d_in[5];
    float* out = (float*)d_out;

    int E = in_sizes[0] / 2;
    int N = in_sizes[1] / D;
    const int* src = ei;
    const int* dst = ei + E;

    auto al = [](size_t x) { return (x + 255) & ~(size_t)255; };
    char* ws = (char*)d_ws;
    size_t off = 0;
    int* cnt = (int*)(ws + off);      off = al(off + (size_t)N * 4);
    int* rowptr = (int*)(ws + off);   off = al(off + ((size_t)N + 1) * 4);
    int* cursor = (int*)(ws + off);   off = al(off + (size_t)N * 4);
    int* bsums = (int*)(ws + off);    off = al(off + 64 * 4);
    int* csr = (int*)(ws + off);      off = al(off + (size_t)E * 4);
    float* dinv = (float*)(ws + off); off = al(off + (size_t)N * 4);
    float* g = (float*)(ws + off);    off = al(off + (size_t)N * D * 4);
    float* x = out;  // reuse d_out as the layer-1 activation buffer

    int nb_scan = (N + 2047) / 2048;

    hipLaunchKernelGGL(k_zero, dim3((N + 255) / 256), dim3(256), 0, stream, cnt, N);
    hipLaunchKernelGGL(k_hist, dim3((E + 255) / 256), dim3(256), 0, stream, dst, cnt, E);
    hipLaunchKernelGGL(k_scan1, dim3(nb_scan), dim3(256), 0, stream, cnt, rowptr, bsums, N);
    hipLaunchKernelGGL(k_scan2, dim3((N + 255) / 256), dim3(256), 0, stream,
                       rowptr, cursor, dinv, cnt, bsums, N, nb_scan);
    hipLaunchKernelGGL(k_fill, dim3((E + 255) / 256), dim3(256), 0, stream,
                       src, dst, cursor, csr, E);

    // layer 1: g = (emb @ W1) * dinv ; x = relu(agg + b1)
    hipLaunchKernelGGL(k_gemm_scale, dim3((N + 31) / 32), dim3(256), 0, stream,
                       emb, W1, dinv, g, N);
    hipLaunchKernelGGL(k_agg, dim3((N + 3) / 4), dim3(256), 0, stream,
                       g, rowptr, csr, dinv, b1, x, N, 1);

    // layer 2: g = (x @ W2) * dinv ; out = agg + b2
    hipLaunchKernelGGL(k_gemm_scale, dim3((N + 31) / 32), dim3(256), 0, stream,
                       x, W2, dinv, g, N);
    hipLaunchKernelGGL(k_agg, dim3((N + 3) / 4), dim3(256), 0, stream,
                       g, rowptr, csr, dinv, b2, out, N, 0);
}

// Round 3
// 198.628 us; speedup vs baseline: 3.9299x; 3.9299x over previous
//
#include <hip/hip_runtime.h>

#define D 64

// ---------------- CSR build (unchanged — control group) ----------------

__global__ void k_zero(int* __restrict__ p, int n) {
    int i = blockIdx.x * blockDim.x + threadIdx.x;
    if (i < n) p[i] = 0;
}

__global__ void k_hist(const int* __restrict__ dst, int* __restrict__ cnt, int e) {
    int i = blockIdx.x * blockDim.x + threadIdx.x;
    if (i < e) atomicAdd(&cnt[dst[i]], 1);
}

__global__ void k_scan1(const int* __restrict__ cnt, int* __restrict__ rowptr,
                        int* __restrict__ bsums, int n) {
    __shared__ int lds[256];
    int tid = threadIdx.x;
    int base = blockIdx.x * 2048 + tid * 8;
    int v[8];
    int s = 0;
#pragma unroll
    for (int j = 0; j < 8; ++j) {
        int idx = base + j;
        v[j] = (idx < n) ? cnt[idx] : 0;
        s += v[j];
    }
    lds[tid] = s;
    __syncthreads();
    for (int off = 1; off < 256; off <<= 1) {
        int t = (tid >= off) ? lds[tid - off] : 0;
        __syncthreads();
        lds[tid] += t;
        __syncthreads();
    }
    int run = lds[tid] - s;
#pragma unroll
    for (int j = 0; j < 8; ++j) {
        int idx = base + j;
        if (idx < n) rowptr[idx] = run;
        run += v[j];
    }
    if (tid == 255) bsums[blockIdx.x] = lds[255];
}

__global__ void k_scan2(int* __restrict__ rowptr, int* __restrict__ cursor,
                        float* __restrict__ dinv, const int* __restrict__ cnt,
                        const int* __restrict__ bsums, int n, int nb) {
    __shared__ int s_off;
    int i = blockIdx.x * blockDim.x + threadIdx.x;
    int b = (blockIdx.x * blockDim.x) >> 11;
    if (threadIdx.x == 0) {
        int o = 0;
        for (int j = 0; j < b; ++j) o += bsums[j];
        s_off = o;
    }
    __syncthreads();
    if (i < n) {
        int rp = rowptr[i] + s_off;
        rowptr[i] = rp;
        cursor[i] = rp;
        dinv[i] = rsqrtf((float)(cnt[i] + 1));
    }
    if (blockIdx.x == 0 && threadIdx.x == 0) {
        int t = 0;
        for (int j = 0; j < nb; ++j) t += bsums[j];
        rowptr[n] = t;
    }
}

__global__ void k_fill(const int* __restrict__ src, const int* __restrict__ dst,
                       int* __restrict__ cursor, int* __restrict__ csr, int e) {
    int i = blockIdx.x * blockDim.x + threadIdx.x;
    if (i < e) {
        int d = dst[i];
        int pos = atomicAdd(&cursor[d], 1);
        csr[pos] = src[i];
    }
}

// ---------------- compute ----------------

// G[r][c] = dinv[r] * sum_k X[r][k] * W[k][c]
// Persistent blocks; 16 rows per tile; thread = (row_local = tid>>4, c4 = tid&15),
// each thread computes one float4 of output. One dwordx4 load + one dwordx4 store
// per thread per tile. W staged to LDS once per block.
__global__ __launch_bounds__(256) void k_gemm2(const float* __restrict__ X,
                                               const float* __restrict__ W,
                                               const float* __restrict__ dinv,
                                               float* __restrict__ G, int n, int ntiles) {
    __shared__ float Ws[D][D];       // 16 KB
    __shared__ float Xs[16][D + 4];  // padded: rows 4-apart in banks -> conflict-free
    int tid = threadIdx.x;
    int rl = tid >> 4;   // 0..15
    int c4 = tid & 15;   // 0..15

    for (int i = tid; i < (D * D) / 4; i += 256)
        reinterpret_cast<float4*>(&Ws[0][0])[i] = reinterpret_cast<const float4*>(W)[i];

    for (int tile = blockIdx.x; tile < ntiles; tile += gridDim.x) {
        int rowbase = tile * 16;
        int row = rowbase + rl;
        __syncthreads();  // Xs from previous tile fully consumed
        {
            float4 v = make_float4(0.f, 0.f, 0.f, 0.f);
            if (row < n) v = reinterpret_cast<const float4*>(X)[(size_t)row * 16 + c4];
            *reinterpret_cast<float4*>(&Xs[rl][c4 * 4]) = v;
        }
        __syncthreads();

        float4 acc = make_float4(0.f, 0.f, 0.f, 0.f);
#pragma unroll
        for (int k = 0; k < D; ++k) {
            float xk = Xs[rl][k];
            float4 w = *reinterpret_cast<const float4*>(&Ws[k][c4 * 4]);
            acc.x += xk * w.x;
            acc.y += xk * w.y;
            acc.z += xk * w.z;
            acc.w += xk * w.w;
        }
        if (row < n) {
            float dv = dinv[row];
            acc.x *= dv; acc.y *= dv; acc.z *= dv; acc.w *= dv;
            reinterpret_cast<float4*>(G)[(size_t)row * 16 + c4] = acc;
        }
    }
}

// out[i] = dinv[i]*(G[i] + sum_{src in row i} G[src]) + b ; optional relu.
// One wave per row. lane = (eq = lane>>4 edge subgroup, c4 = lane&15 column quad).
// Each lane gathers float4 covering 4 edges per iteration; shfl_xor reduce.
__global__ __launch_bounds__(256) void k_agg2(const float* __restrict__ G,
                                              const int* __restrict__ rowptr,
                                              const int* __restrict__ csr,
                                              const float* __restrict__ dinv,
                                              const float* __restrict__ bias,
                                              float* __restrict__ out,
                                              int n, int do_relu) {
    int wid = (blockIdx.x * blockDim.x + threadIdx.x) >> 6;
    if (wid >= n) return;
    int lane = threadIdx.x & 63;
    int eq = lane >> 4;
    int c4 = lane & 15;
    int beg = rowptr[wid];
    int end = rowptr[wid + 1];

    float4 acc = make_float4(0.f, 0.f, 0.f, 0.f);
    for (int e = beg + eq; e < end; e += 4) {
        int s = csr[e];
        float4 v = reinterpret_cast<const float4*>(G)[(size_t)s * 16 + c4];
        acc.x += v.x; acc.y += v.y; acc.z += v.z; acc.w += v.w;
    }
    // reduce across the 4 edge subgroups (lane ^ 16, lane ^ 32)
#pragma unroll
    for (int off = 16; off < 64; off <<= 1) {
        acc.x += __shfl_xor(acc.x, off);
        acc.y += __shfl_xor(acc.y, off);
        acc.z += __shfl_xor(acc.z, off);
        acc.w += __shfl_xor(acc.w, off);
    }
    if (eq == 0) {
        float4 s4 = reinterpret_cast<const float4*>(G)[(size_t)wid * 16 + c4];
        float dv = dinv[wid];
        float4 b4 = reinterpret_cast<const float4*>(bias)[c4];
        float4 o;
        o.x = (acc.x + s4.x) * dv + b4.x;
        o.y = (acc.y + s4.y) * dv + b4.y;
        o.z = (acc.z + s4.z) * dv + b4.z;
        o.w = (acc.w + s4.w) * dv + b4.w;
        if (do_relu) {
            o.x = fmaxf(o.x, 0.f); o.y = fmaxf(o.y, 0.f);
            o.z = fmaxf(o.z, 0.f); o.w = fmaxf(o.w, 0.f);
        }
        reinterpret_cast<float4*>(out)[(size_t)wid * 16 + c4] = o;
    }
}

// ---------------- launch ----------------

extern "C" void kernel_launch(void* const* d_in, const int* in_sizes, int n_in,
                              void* d_out, int out_size, void* d_ws, size_t ws_size,
                              hipStream_t stream) {
    const int* ei = (const int*)d_in[0];
    const float* emb = (const float*)d_in[1];
    const float* W1 = (const float*)d_in[2];
    const float* b1 = (const float*)d_in[3];
    const float* W2 = (const float*)d_in[4];
    const float* b2 = (const float*)d_in[5];
    float* out = (float*)d_out;

    int E = in_sizes[0] / 2;
    int N = in_sizes[1] / D;
    const int* src = ei;
    const int* dst = ei + E;

    auto al = [](size_t x) { return (x + 255) & ~(size_t)255; };
    char* ws = (char*)d_ws;
    size_t off = 0;
    int* cnt = (int*)(ws + off);      off = al(off + (size_t)N * 4);
    int* rowptr = (int*)(ws + off);   off = al(off + ((size_t)N + 1) * 4);
    int* cursor = (int*)(ws + off);   off = al(off + (size_t)N * 4);
    int* bsums = (int*)(ws + off);    off = al(off + 64 * 4);
    int* csr = (int*)(ws + off);      off = al(off + (size_t)E * 4);
    float* dinv = (float*)(ws + off); off = al(off + (size_t)N * 4);
    float* g = (float*)(ws + off);    off = al(off + (size_t)N * D * 4);
    float* x = out;  // reuse d_out as the layer-1 activation buffer

    int nb_scan = (N + 2047) / 2048;
    int ntiles = (N + 15) / 16;
    int gemm_blocks = 1024;

    hipLaunchKernelGGL(k_zero, dim3((N + 255) / 256), dim3(256), 0, stream, cnt, N);
    hipLaunchKernelGGL(k_hist, dim3((E + 255) / 256), dim3(256), 0, stream, dst, cnt, E);
    hipLaunchKernelGGL(k_scan1, dim3(nb_scan), dim3(256), 0, stream, cnt, rowptr, bsums, N);
    hipLaunchKernelGGL(k_scan2, dim3((N + 255) / 256), dim3(256), 0, stream,
                       rowptr, cursor, dinv, cnt, bsums, N, nb_scan);
    hipLaunchKernelGGL(k_fill, dim3((E + 255) / 256), dim3(256), 0, stream,
                       src, dst, cursor, csr, E);

    // layer 1
    hipLaunchKernelGGL(k_gemm2, dim3(gemm_blocks), dim3(256), 0, stream,
                       emb, W1, dinv, g, N, ntiles);
    hipLaunchKernelGGL(k_agg2, dim3((N + 3) / 4), dim3(256), 0, stream,
                       g, rowptr, csr, dinv, b1, x, N, 1);

    // layer 2
    hipLaunchKernelGGL(k_gemm2, dim3(gemm_blocks), dim3(256), 0, stream,
                       x, W2, dinv, g, N, ntiles);
    hipLaunchKernelGGL(k_agg2, dim3((N + 3) / 4), dim3(256), 0, stream,
                       g, rowptr, csr, dinv, b2, out, N, 0);
}